// Round 3
// baseline (306.635 us; speedup 1.0000x reference)
//
#include <hip/hip_runtime.h>

typedef short bf16x8 __attribute__((ext_vector_type(8)));
typedef float f32x16 __attribute__((ext_vector_type(16)));

#define BIG_F 1e10f
constexpr int B = 16;
constexpr int N = 4096;
constexpr int ROWS = 128;         // x-rows per block
constexpr int COLS = 512;         // y-cols per block (one-shot, no chunk loop)
constexpr int NRB = N / ROWS;     // 32 row-blocks
constexpr int NCB = N / COLS;     // 8 col-blocks

// truncating bf16 hi/lo split: v ~= hi + lo
__device__ __forceinline__ void split(float v, unsigned& h, unsigned& l) {
    unsigned hb = __float_as_uint(v) & 0xFFFF0000u;
    h = hb >> 16;
    float r = v - __uint_as_float(hb);
    l = __float_as_uint(r) >> 16;
}

__device__ __forceinline__ float min3f(float a, float b, float c) {
    return fminf(fminf(a, b), c);   // fuses to v_min3_f32
}

__device__ __forceinline__ float vmin16(f32x16 C) {
    float u0 = min3f(C[0], C[1], C[2]);
    float u1 = min3f(C[3], C[4], C[5]);
    float u2 = min3f(C[6], C[7], C[8]);
    float u3 = min3f(C[9], C[10], C[11]);
    float u4 = min3f(C[12], C[13], C[14]);
    return min3f(min3f(u0, u1, u2), fminf(u3, u4), C[15]);
}

// P[n,m] = xx[n] + yy[m] - 2 x_n . y_m (+BIG on masked n / m) via ONE
// mfma_f32_32x32x16_bf16 per 32x32 tile (all 16 K-slots used):
//   A_k(n) = [ah0..2, ah0..2, al0..2, al0..2, xxh, xxl, 1, 1]   (ah+al = -2x)
//   B_k(m) = [yh0..2, yl0..2, yh0..2, yl0..2, 1, 1, qh, ql]     (qh+ql = yy)
// LDS: K-split fragments [khalf][point][8] (16B/point/half, b128 reads).
// One-shot block: pack -> sync -> 8 MFMA-pair iters -> sync -> combine.
// __launch_bounds__(256,4): cap VGPR at 128 so 4 blocks/CU co-reside.
__global__ __launch_bounds__(256, 4) void chamfer_mfma(
    const float* __restrict__ x, const float* __restrict__ y,
    const int* __restrict__ mask,
    float* __restrict__ rowpart,   // [B][NCB][N] row-min partials (over 512 cols)
    float* __restrict__ colpart,   // [B][NRB][N] col-min partials (over 128 rows)
    float* __restrict__ out)
{
    const int rb = blockIdx.x & 31;   // consecutive blocks share the y-slice (L2)
    const int cb = blockIdx.x >> 5;
    const int b  = blockIdx.y;
    const int t  = threadIdx.x;

    __shared__ __align__(16) unsigned short Apack[2][ROWS][8];   // 4 KB
    __shared__ __align__(16) unsigned short Bpack[2][COLS][8];   // 16 KB
    __shared__ float colbuf[4][COLS];                            // 8 KB (per wave)

    if (blockIdx.x == 0 && b == 0 && t == 0) out[0] = 0.0f;  // finalize is next

    const float* xb = x + (size_t)b * 3 * N;
    const float* yb = y + (size_t)b * 3 * N;
    const int*   mb = mask + b * N;

    // ---- pack A: this block's 128 x-points ----
    if (t < ROWS) {
        int n = rb * ROWS + t;
        float x0 = xb[n], x1 = xb[N + n], x2 = xb[2 * N + n];
        float madd = mb[n] ? 0.0f : BIG_F;
        float xx = fmaf(x2, x2, fmaf(x1, x1, x0 * x0)) + madd;
        unsigned h0, l0, h1, l1, h2, l2, xh, xl;
        split(-2.0f * x0, h0, l0);
        split(-2.0f * x1, h1, l1);
        split(-2.0f * x2, h2, l2);
        split(xx, xh, xl);
        // k0..7  = ah0 ah1 ah2 ah0 ah1 ah2 al0 al1
        uint4 w0 = { h0 | (h1 << 16), h2 | (h0 << 16), h1 | (h2 << 16), l0 | (l1 << 16) };
        *(uint4*)&Apack[0][t][0] = w0;
        // k8..15 = al2 al0 al1 al2 xxh xxl 1 1
        uint4 w1 = { l2 | (l0 << 16), l1 | (l2 << 16), xh | (xl << 16), 0x3F803F80u };
        *(uint4*)&Apack[1][t][0] = w1;
    }

    // ---- pack B: this block's 512 y-points (2 per thread) ----
#pragma unroll
    for (int i = 0; i < 2; ++i) {
        int c = t + i * 256;
        int m = cb * COLS + c;
        float y0 = yb[m], y1 = yb[N + m], y2 = yb[2 * N + m];
        float madd = mb[m] ? 0.0f : BIG_F;
        float yy = fmaf(y2, y2, fmaf(y1, y1, y0 * y0)) + madd;
        unsigned h0, l0, h1, l1, h2, l2, qh, ql;
        split(y0, h0, l0);
        split(y1, h1, l1);
        split(y2, h2, l2);
        split(yy, qh, ql);
        unsigned u0 = h0 | (h1 << 16);   // yh0 yh1
        unsigned u1 = h2 | (l0 << 16);   // yh2 yl0
        unsigned u2 = l1 | (l2 << 16);   // yl1 yl2
        // k0..7  = yh0 yh1 yh2 yl0 yl1 yl2 yh0 yh1
        uint4 w0 = { u0, u1, u2, u0 };
        *(uint4*)&Bpack[0][c][0] = w0;
        // k8..15 = yh2 yl0 yl1 yl2 1 1 qh ql
        uint4 w1 = { u1, u2, 0x3F803F80u, qh | (ql << 16) };
        *(uint4*)&Bpack[1][c][0] = w1;
    }
    __syncthreads();

    const int w    = t >> 6;    // wave 0..3, owns rows w*32..w*32+31
    const int L    = t & 63;
    const int half = L >> 5;    // k-half 0/1
    const int lc   = L & 31;    // row/col within 32-tile

    bf16x8 afr = *(const bf16x8*)&Apack[half][w * 32 + lc][0];
    const unsigned short* Bb = &Bpack[half][lc][0];

    float rm[16];
#pragma unroll
    for (int r = 0; r < 16; ++r) rm[r] = 1e30f;

    const f32x16 z16 = {0.f,0.f,0.f,0.f,0.f,0.f,0.f,0.f,
                        0.f,0.f,0.f,0.f,0.f,0.f,0.f,0.f};

#pragma unroll
    for (int p = 0; p < 8; ++p) {          // 8 col-pairs of 32 = 512 cols
        bf16x8 bf0 = *(const bf16x8*)(Bb + p * 512);
        bf16x8 bf1 = *(const bf16x8*)(Bb + p * 512 + 256);
        f32x16 C0 = __builtin_amdgcn_mfma_f32_32x32x16_bf16(afr, bf0, z16, 0, 0, 0);
        f32x16 C1 = __builtin_amdgcn_mfma_f32_32x32x16_bf16(afr, bf1, z16, 0, 0, 0);
        // row-mins: C[r] is row w*32 + (r&3)+8*(r>>2)+4*half, col = p*64(+32)+lc
#pragma unroll
        for (int r = 0; r < 16; ++r) rm[r] = min3f(rm[r], C0[r], C1[r]);
        // col partial: min over this half's 16 rows, then cross-half via shfl
        float v0 = vmin16(C0), v1 = vmin16(C1);
        v0 = fminf(v0, __shfl_xor(v0, 32));
        v1 = fminf(v1, __shfl_xor(v1, 32));
        if (half == 0) {
            colbuf[w][p * 64 + lc]      = v0;   // min over wave's 32 rows
            colbuf[w][p * 64 + 32 + lc] = v1;
        }
    }

    // finish row-mins: reduce across the 32 col-lanes (stays within 32-lane half)
#pragma unroll
    for (int off = 1; off <= 16; off <<= 1)
#pragma unroll
        for (int r = 0; r < 16; ++r)
            rm[r] = fminf(rm[r], __shfl_xor(rm[r], off));
    if (lc == 0) {
        float* rp = rowpart + ((size_t)b * NCB + cb) * N + rb * ROWS + w * 32 + half * 4;
#pragma unroll
        for (int r = 0; r < 16; ++r)
            rp[(r & 3) + 8 * (r >> 2)] = rm[r];
    }

    __syncthreads();
    // combine 4 waves' col partials -> block col partial (min over 128 rows)
    float* cpo = colpart + ((size_t)b * NRB + rb) * N + cb * COLS;
#pragma unroll
    for (int i = 0; i < 2; ++i) {
        int c = t + i * 256;
        float v = fminf(fminf(colbuf[0][c], colbuf[1][c]),
                        fminf(colbuf[2][c], colbuf[3][c]));
        cpo[c] = v;
    }
}

__global__ __launch_bounds__(256) void finalize_kernel(
    const int* __restrict__ mask,
    const float* __restrict__ rowpart, const float* __restrict__ colpart,
    float* __restrict__ out)
{
    const int b = blockIdx.x & 15;
    const int q = blockIdx.x >> 4;   // quarter 0..3
    const int t = threadIdx.x;
    const int* mrow = mask + b * N;

    // full-batch valid count (L2-resident)
    int cnt = 0;
    for (int i = t; i < N / 4; i += 256) {
        int4 mk = ((const int4*)mrow)[i];
        cnt += mk.x + mk.y + mk.z + mk.w;
    }

    const int p0 = q * 1024 + t * 4;

    // min over the 32 col-partial slabs
    const float* cp = colpart + (size_t)b * NRB * N + p0;
    float4 mn = *(const float4*)cp;
#pragma unroll 4
    for (int pb = 1; pb < NRB; ++pb) {
        float4 v = *(const float4*)(cp + (size_t)pb * N);
        mn.x = fminf(mn.x, v.x); mn.y = fminf(mn.y, v.y);
        mn.z = fminf(mn.z, v.z); mn.w = fminf(mn.w, v.w);
    }
    // min over the 8 row-partial slabs
    const float* rp = rowpart + (size_t)b * NCB * N + p0;
    float4 rn = *(const float4*)rp;
#pragma unroll
    for (int pb = 1; pb < NCB; ++pb) {
        float4 v = *(const float4*)(rp + (size_t)pb * N);
        rn.x = fminf(rn.x, v.x); rn.y = fminf(rn.y, v.y);
        rn.z = fminf(rn.z, v.z); rn.w = fminf(rn.w, v.w);
    }
    int4 mk = *(const int4*)(mrow + p0);
    float s = (mk.x ? (mn.x + rn.x) : 0.f) + (mk.y ? (mn.y + rn.y) : 0.f)
            + (mk.z ? (mn.z + rn.z) : 0.f) + (mk.w ? (mn.w + rn.w) : 0.f);

    for (int off = 32; off > 0; off >>= 1) {
        s   += __shfl_down(s, off);
        cnt += __shfl_down(cnt, off);
    }
    __shared__ float rs[4];
    __shared__ int   rc[4];
    const int wv = t >> 6;
    if ((t & 63) == 0) { rs[wv] = s; rc[wv] = cnt; }
    __syncthreads();
    if (t == 0) {
        float S = rs[0] + rs[1] + rs[2] + rs[3];
        float C = (float)(rc[0] + rc[1] + rc[2] + rc[3]);
        atomicAdd(out, (S / C) * (1.0f / 16.0f));
    }
}

extern "C" void kernel_launch(void* const* d_in, const int* in_sizes, int n_in,
                              void* d_out, int out_size, void* d_ws, size_t ws_size,
                              hipStream_t stream) {
    const float* x    = (const float*)d_in[0];
    const float* y    = (const float*)d_in[1];
    const int*   mask = (const int*)d_in[2];

    float* rowpart = (float*)d_ws;                      // B*NCB*N = 2 MB
    float* colpart = rowpart + (size_t)B * NCB * N;     // B*NRB*N = 8 MB

    chamfer_mfma<<<dim3(NRB * NCB, B), 256, 0, stream>>>(
        x, y, mask, rowpart, colpart, (float*)d_out);
    finalize_kernel<<<dim3(64), 256, 0, stream>>>(
        mask, rowpart, colpart, (float*)d_out);
}

// Round 4
// 95.369 us; speedup vs baseline: 3.2152x; 3.2152x over previous
//
#include <hip/hip_runtime.h>

typedef short bf16x8 __attribute__((ext_vector_type(8)));
typedef float f32x16 __attribute__((ext_vector_type(16)));

#define BIG_F 1e10f
constexpr int B = 16;
constexpr int N = 4096;
constexpr int ROWS = 128;         // x-rows per block
constexpr int COLS = 512;         // y-cols per block (one-shot, no chunk loop)
constexpr int NRB = N / ROWS;     // 32 row-blocks
constexpr int NCB = N / COLS;     // 8 col-blocks

// truncating bf16 hi/lo split: v ~= hi + lo
__device__ __forceinline__ void split(float v, unsigned& h, unsigned& l) {
    unsigned hb = __float_as_uint(v) & 0xFFFF0000u;
    h = hb >> 16;
    float r = v - __uint_as_float(hb);
    l = __float_as_uint(r) >> 16;
}

__device__ __forceinline__ float min3f(float a, float b, float c) {
    return fminf(fminf(a, b), c);   // fuses to v_min3_f32
}

__device__ __forceinline__ float vmin16(f32x16 C) {
    float u0 = min3f(C[0], C[1], C[2]);
    float u1 = min3f(C[3], C[4], C[5]);
    float u2 = min3f(C[6], C[7], C[8]);
    float u3 = min3f(C[9], C[10], C[11]);
    float u4 = min3f(C[12], C[13], C[14]);
    return min3f(min3f(u0, u1, u2), fminf(u3, u4), C[15]);
}

// P[n,m] = xx[n] + yy[m] - 2 x_n . y_m (+BIG on masked n / m) via ONE
// mfma_f32_32x32x16_bf16 per 32x32 tile (all 16 K-slots used):
//   A_k(n) = [ah0..2, ah0..2, al0..2, al0..2, xxh, xxl, 1, 1]   (ah+al = -2x)
//   B_k(m) = [yh0..2, yl0..2, yh0..2, yl0..2, 1, 1, qh, ql]     (qh+ql = yy)
// LDS: K-split fragments [khalf][point][8] (16B/point/half, b128 reads).
// One-shot block: pack -> sync -> 8 MFMA-pair iters -> sync -> combine.
// launch_bounds(256,3): ~170-reg budget, 3 blocks/CU — NO spill (R3's (256,4)
// cap of 128 spilled ~700B/thread -> 742MB scratch writes, 6x regression).
// unroll 2 keeps the compiler from hoisting all 16 ds_read_b128 at once.
__global__ __launch_bounds__(256, 3) void chamfer_mfma(
    const float* __restrict__ x, const float* __restrict__ y,
    const int* __restrict__ mask,
    float* __restrict__ rowpart,   // [B][NCB][N] row-min partials (over 512 cols)
    float* __restrict__ colpart,   // [B][NRB][N] col-min partials (over 128 rows)
    float* __restrict__ out)
{
    const int rb = blockIdx.x & 31;   // consecutive blocks share the y-slice (L2)
    const int cb = blockIdx.x >> 5;
    const int b  = blockIdx.y;
    const int t  = threadIdx.x;

    __shared__ __align__(16) unsigned short Apack[2][ROWS][8];   // 4 KB
    __shared__ __align__(16) unsigned short Bpack[2][COLS][8];   // 16 KB
    __shared__ float colbuf[4][COLS];                            // 8 KB (per wave)

    if (blockIdx.x == 0 && b == 0 && t == 0) out[0] = 0.0f;  // finalize is next

    const float* xb = x + (size_t)b * 3 * N;
    const float* yb = y + (size_t)b * 3 * N;
    const int*   mb = mask + b * N;

    // ---- pack A: this block's 128 x-points ----
    if (t < ROWS) {
        int n = rb * ROWS + t;
        float x0 = xb[n], x1 = xb[N + n], x2 = xb[2 * N + n];
        float madd = mb[n] ? 0.0f : BIG_F;
        float xx = fmaf(x2, x2, fmaf(x1, x1, x0 * x0)) + madd;
        unsigned h0, l0, h1, l1, h2, l2, xh, xl;
        split(-2.0f * x0, h0, l0);
        split(-2.0f * x1, h1, l1);
        split(-2.0f * x2, h2, l2);
        split(xx, xh, xl);
        // k0..7  = ah0 ah1 ah2 ah0 ah1 ah2 al0 al1
        uint4 w0 = { h0 | (h1 << 16), h2 | (h0 << 16), h1 | (h2 << 16), l0 | (l1 << 16) };
        *(uint4*)&Apack[0][t][0] = w0;
        // k8..15 = al2 al0 al1 al2 xxh xxl 1 1
        uint4 w1 = { l2 | (l0 << 16), l1 | (l2 << 16), xh | (xl << 16), 0x3F803F80u };
        *(uint4*)&Apack[1][t][0] = w1;
    }

    // ---- pack B: this block's 512 y-points (2 per thread) ----
#pragma unroll
    for (int i = 0; i < 2; ++i) {
        int c = t + i * 256;
        int m = cb * COLS + c;
        float y0 = yb[m], y1 = yb[N + m], y2 = yb[2 * N + m];
        float madd = mb[m] ? 0.0f : BIG_F;
        float yy = fmaf(y2, y2, fmaf(y1, y1, y0 * y0)) + madd;
        unsigned h0, l0, h1, l1, h2, l2, qh, ql;
        split(y0, h0, l0);
        split(y1, h1, l1);
        split(y2, h2, l2);
        split(yy, qh, ql);
        unsigned u0 = h0 | (h1 << 16);   // yh0 yh1
        unsigned u1 = h2 | (l0 << 16);   // yh2 yl0
        unsigned u2 = l1 | (l2 << 16);   // yl1 yl2
        // k0..7  = yh0 yh1 yh2 yl0 yl1 yl2 yh0 yh1
        uint4 w0 = { u0, u1, u2, u0 };
        *(uint4*)&Bpack[0][c][0] = w0;
        // k8..15 = yh2 yl0 yl1 yl2 1 1 qh ql
        uint4 w1 = { u1, u2, 0x3F803F80u, qh | (ql << 16) };
        *(uint4*)&Bpack[1][c][0] = w1;
    }
    __syncthreads();

    const int w    = t >> 6;    // wave 0..3, owns rows w*32..w*32+31
    const int L    = t & 63;
    const int half = L >> 5;    // k-half 0/1
    const int lc   = L & 31;    // row/col within 32-tile

    bf16x8 afr = *(const bf16x8*)&Apack[half][w * 32 + lc][0];
    const unsigned short* Bb = &Bpack[half][lc][0];

    float rm[16];
#pragma unroll
    for (int r = 0; r < 16; ++r) rm[r] = 1e30f;

    const f32x16 z16 = {0.f,0.f,0.f,0.f,0.f,0.f,0.f,0.f,
                        0.f,0.f,0.f,0.f,0.f,0.f,0.f,0.f};

#pragma unroll 2
    for (int p = 0; p < 8; ++p) {          // 8 col-pairs of 32 = 512 cols
        bf16x8 bf0 = *(const bf16x8*)(Bb + p * 512);
        bf16x8 bf1 = *(const bf16x8*)(Bb + p * 512 + 256);
        f32x16 C0 = __builtin_amdgcn_mfma_f32_32x32x16_bf16(afr, bf0, z16, 0, 0, 0);
        f32x16 C1 = __builtin_amdgcn_mfma_f32_32x32x16_bf16(afr, bf1, z16, 0, 0, 0);
        // row-mins: C[r] is row w*32 + (r&3)+8*(r>>2)+4*half, col = p*64(+32)+lc
#pragma unroll
        for (int r = 0; r < 16; ++r) rm[r] = min3f(rm[r], C0[r], C1[r]);
        // col partial: min over this half's 16 rows, then cross-half via shfl
        float v0 = vmin16(C0), v1 = vmin16(C1);
        v0 = fminf(v0, __shfl_xor(v0, 32));
        v1 = fminf(v1, __shfl_xor(v1, 32));
        if (half == 0) {
            colbuf[w][p * 64 + lc]      = v0;   // min over wave's 32 rows
            colbuf[w][p * 64 + 32 + lc] = v1;
        }
    }

    // finish row-mins: reduce across the 32 col-lanes (stays within 32-lane half)
#pragma unroll
    for (int off = 1; off <= 16; off <<= 1)
#pragma unroll
        for (int r = 0; r < 16; ++r)
            rm[r] = fminf(rm[r], __shfl_xor(rm[r], off));
    if (lc == 0) {
        float* rp = rowpart + ((size_t)b * NCB + cb) * N + rb * ROWS + w * 32 + half * 4;
#pragma unroll
        for (int r = 0; r < 16; ++r)
            rp[(r & 3) + 8 * (r >> 2)] = rm[r];
    }

    __syncthreads();
    // combine 4 waves' col partials -> block col partial (min over 128 rows)
    float* cpo = colpart + ((size_t)b * NRB + rb) * N + cb * COLS;
#pragma unroll
    for (int i = 0; i < 2; ++i) {
        int c = t + i * 256;
        float v = fminf(fminf(colbuf[0][c], colbuf[1][c]),
                        fminf(colbuf[2][c], colbuf[3][c]));
        cpo[c] = v;
    }
}

__global__ __launch_bounds__(256) void finalize_kernel(
    const int* __restrict__ mask,
    const float* __restrict__ rowpart, const float* __restrict__ colpart,
    float* __restrict__ out)
{
    const int b = blockIdx.x & 15;
    const int q = blockIdx.x >> 4;   // quarter 0..3
    const int t = threadIdx.x;
    const int* mrow = mask + b * N;

    // full-batch valid count (L2-resident)
    int cnt = 0;
    for (int i = t; i < N / 4; i += 256) {
        int4 mk = ((const int4*)mrow)[i];
        cnt += mk.x + mk.y + mk.z + mk.w;
    }

    const int p0 = q * 1024 + t * 4;

    // min over the 32 col-partial slabs
    const float* cp = colpart + (size_t)b * NRB * N + p0;
    float4 mn = *(const float4*)cp;
#pragma unroll 4
    for (int pb = 1; pb < NRB; ++pb) {
        float4 v = *(const float4*)(cp + (size_t)pb * N);
        mn.x = fminf(mn.x, v.x); mn.y = fminf(mn.y, v.y);
        mn.z = fminf(mn.z, v.z); mn.w = fminf(mn.w, v.w);
    }
    // min over the 8 row-partial slabs
    const float* rp = rowpart + (size_t)b * NCB * N + p0;
    float4 rn = *(const float4*)rp;
#pragma unroll
    for (int pb = 1; pb < NCB; ++pb) {
        float4 v = *(const float4*)(rp + (size_t)pb * N);
        rn.x = fminf(rn.x, v.x); rn.y = fminf(rn.y, v.y);
        rn.z = fminf(rn.z, v.z); rn.w = fminf(rn.w, v.w);
    }
    int4 mk = *(const int4*)(mrow + p0);
    float s = (mk.x ? (mn.x + rn.x) : 0.f) + (mk.y ? (mn.y + rn.y) : 0.f)
            + (mk.z ? (mn.z + rn.z) : 0.f) + (mk.w ? (mn.w + rn.w) : 0.f);

    for (int off = 32; off > 0; off >>= 1) {
        s   += __shfl_down(s, off);
        cnt += __shfl_down(cnt, off);
    }
    __shared__ float rs[4];
    __shared__ int   rc[4];
    const int wv = t >> 6;
    if ((t & 63) == 0) { rs[wv] = s; rc[wv] = cnt; }
    __syncthreads();
    if (t == 0) {
        float S = rs[0] + rs[1] + rs[2] + rs[3];
        float C = (float)(rc[0] + rc[1] + rc[2] + rc[3]);
        atomicAdd(out, (S / C) * (1.0f / 16.0f));
    }
}

extern "C" void kernel_launch(void* const* d_in, const int* in_sizes, int n_in,
                              void* d_out, int out_size, void* d_ws, size_t ws_size,
                              hipStream_t stream) {
    const float* x    = (const float*)d_in[0];
    const float* y    = (const float*)d_in[1];
    const int*   mask = (const int*)d_in[2];

    float* rowpart = (float*)d_ws;                      // B*NCB*N = 2 MB
    float* colpart = rowpart + (size_t)B * NCB * N;     // B*NRB*N = 8 MB

    chamfer_mfma<<<dim3(NRB * NCB, B), 256, 0, stream>>>(
        x, y, mask, rowpart, colpart, (float*)d_out);
    finalize_kernel<<<dim3(64), 256, 0, stream>>>(
        mask, rowpart, colpart, (float*)d_out);
}